// Round 1
// baseline (354.650 us; speedup 1.0000x reference)
//
#include <hip/hip_runtime.h>

typedef __bf16 bf16x8 __attribute__((ext_vector_type(8)));
typedef float f32x4 __attribute__((ext_vector_type(4)));

__device__ __forceinline__ unsigned short f2bf(float f) {
    union { float f; unsigned u; } v; v.f = f;
    unsigned r = (v.u + 0x7FFFu + ((v.u >> 16) & 1u)) >> 16;
    return (unsigned short)r;
}

// ---- weight transpose/cast kernels (run every launch; d_ws is re-poisoned) ----
// W1 (119,1024) f32 -> W1T (1024 x 128) bf16, zero-padded K 119->128
__global__ void conv_w1(const float* __restrict__ W1, unsigned short* __restrict__ W1T) {
    int idx = blockIdx.x * 256 + threadIdx.x;     // 131072 total
    int h = idx >> 7, k = idx & 127;
    float v = (k < 119) ? W1[(size_t)k * 1024 + h] : 0.0f;
    W1T[idx] = f2bf(v);
}
// W2 (1024,256) f32 -> W2T (256 x 1024) bf16
__global__ void conv_w2(const float* __restrict__ W2, unsigned short* __restrict__ W2T) {
    int idx = blockIdx.x * 256 + threadIdx.x;     // 262144 total
    int n = idx >> 10, h = idx & 1023;
    W2T[idx] = f2bf(W2[(size_t)h * 256 + n]);
}

// ---- fused features + MLP ----
// block: 256 threads (4 waves), 64 rows. out[64x256] accumulated in registers.
__global__ __launch_bounds__(256, 2) void mlp_fused(
    const float* __restrict__ hole, const float* __restrict__ board,
    const float* __restrict__ b1, const float* __restrict__ b2,
    const unsigned short* __restrict__ W1T, const unsigned short* __restrict__ W2T,
    float* __restrict__ out)
{
    __shared__ unsigned short Xs[64][136];   // 64 rows x 128 K (bf16), pad->136 for LDS banks
    __shared__ unsigned short Hs[64][72];    // 64 rows x 64 hidden-chunk (bf16), pad->72

    const int tid  = threadIdx.x;
    const int wave = tid >> 6;
    const int lane = tid & 63;
    const int q    = lane >> 4;   // quad
    const int l16  = lane & 15;
    const long r0  = (long)blockIdx.x * 64;

    // ---------------- feature extraction: thread t < 64 handles row r0+t ----------------
    if (tid < 64) {
        const long r = r0 + tid;
        const float4* hp = (const float4*)(hole + r * 52);
        const float4* bp = (const float4*)(board + r * 52);
        unsigned long long hm = 0ull, bm = 0ull;
        #pragma unroll
        for (int i = 0; i < 13; ++i) {
            float4 h4 = hp[i], b4 = bp[i];
            int base = i * 4;
            hm |= ((unsigned long long)(h4.x > 0.5f)) << (base + 0);
            hm |= ((unsigned long long)(h4.y > 0.5f)) << (base + 1);
            hm |= ((unsigned long long)(h4.z > 0.5f)) << (base + 2);
            hm |= ((unsigned long long)(h4.w > 0.5f)) << (base + 3);
            bm |= ((unsigned long long)(b4.x > 0.5f)) << (base + 0);
            bm |= ((unsigned long long)(b4.y > 0.5f)) << (base + 1);
            bm |= ((unsigned long long)(b4.z > 0.5f)) << (base + 2);
            bm |= ((unsigned long long)(b4.w > 0.5f)) << (base + 3);
        }
        const unsigned long long am = hm | bm;   // hole & board disjoint by construction
        const int bcount = __popcll(bm);
        const int hcount = __popcll(hm);

        int pairs_b = 0, pairs_a = 0;
        bool trips_b = false, trips_a = false;
        unsigned prb = 0, pra = 0;
        #pragma unroll
        for (int rr = 0; rr < 13; ++rr) {
            int cb = __popc((unsigned)((bm >> (4 * rr)) & 0xFull));
            int ca = __popc((unsigned)((am >> (4 * rr)) & 0xFull));
            pairs_b += (cb >= 2); trips_b = trips_b || (cb >= 3); prb |= (unsigned)(cb > 0) << rr;
            pairs_a += (ca >= 2); trips_a = trips_a || (ca >= 3); pra |= (unsigned)(ca > 0) << rr;
        }
        const unsigned long long SM = 0x1111111111111ull;  // bits 0,4,...,48
        int bscm = 0, ascm = 0;
        #pragma unroll
        for (int s = 0; s < 4; ++s) {
            int bs = __popcll(bm & (SM << s));
            int as = __popcll(am & (SM << s));
            bscm = bs > bscm ? bs : bscm;
            ascm = as > ascm ? as : ascm;
        }
        float strength = trips_b ? 0.8f : (pairs_b >= 2 ? 0.6f : (pairs_b >= 1 ? 0.4f : 0.2f));
        if (bcount == 0) strength = 0.0f;
        float flush_b = (bscm >= 3 && bcount > 0) ? 1.0f : 0.0f;
        bool sb = false;
        #pragma unroll
        for (int i = 0; i < 13; ++i) sb = sb || (__popc((prb >> i) & 0x1Fu) >= 3);
        float straight_b = (sb && bcount > 0) ? 1.0f : 0.0f;
        float gr0 = (bcount == 0) ? 1.0f : 0.0f;
        float gr3 = (bcount == 3) ? 1.0f : 0.0f;
        float gr4 = (bcount == 4) ? 1.0f : 0.0f;
        float gr5 = (bcount == 5) ? 1.0f : 0.0f;
        float valid = (hcount >= 2 && bcount >= 1) ? 1.0f : 0.0f;
        float flush_draw = (ascm == 4) ? 1.0f : 0.0f;
        float flush_outs = fmaxf(0.0f, 13.0f - (float)ascm) * (1.0f / 13.0f);
        int first = -1;
        #pragma unroll
        for (int i = 0; i < 13; ++i) {
            bool qq = (((pra >> i) & 1u) != 0u) && (__popc((pra >> i) & 0x1Fu) >= 4);
            if (qq && first < 0) first = i;
        }
        float straight_draw = (first >= 0) ? 1.0f : 0.0f;
        float straight_outs = 0.0f;
        if (first >= 0) {
            int c4 = __popc((pra >> first) & 0xFu);
            straight_outs = (c4 >= 4) ? 0.4f : 0.2f;
        }
        float total_outs = flush_draw * flush_outs * 9.0f + straight_draw * straight_outs * 8.0f;
        float remaining = 52.0f - (float)(hcount + bcount);
        float equity = 0.0f;
        if (remaining > 0.0f) equity = fminf(1.0f, total_outs / fmaxf(remaining, 1.0f));
        float hit_pair  = (pairs_a >= 1) ? 1.0f : 0.0f;
        float hit_trips = trips_a ? 1.0f : 0.0f;
        float hit_two   = (pairs_a >= 2) ? 1.0f : 0.0f;

        unsigned short* xrow = &Xs[tid][0];
        #pragma unroll
        for (int i = 0; i < 52; ++i) xrow[i]      = ((hm >> i) & 1ull) ? (unsigned short)0x3F80 : (unsigned short)0;
        #pragma unroll
        for (int i = 0; i < 52; ++i) xrow[52 + i] = ((bm >> i) & 1ull) ? (unsigned short)0x3F80 : (unsigned short)0;
        float feats[15] = { strength, flush_b, straight_b, gr0, gr3, gr4, gr5,
                            valid * flush_draw, valid * flush_outs, valid * straight_draw,
                            valid * straight_outs, valid * equity,
                            valid * hit_pair, valid * hit_trips, valid * hit_two };
        #pragma unroll
        for (int i = 0; i < 15; ++i) xrow[104 + i] = f2bf(feats[i]);
        #pragma unroll
        for (int i = 119; i < 136; ++i) xrow[i] = 0;
    }

    const f32x4 vzero = {0.0f, 0.0f, 0.0f, 0.0f};
    f32x4 acc[4][4];
    #pragma unroll
    for (int a = 0; a < 4; ++a)
        #pragma unroll
        for (int b = 0; b < 4; ++b) acc[a][b] = vzero;

    __syncthreads();

    // ---------------- hidden-dim chunk loop: 16 chunks of 64 ----------------
    for (int c = 0; c < 16; ++c) {
        // phase A: Hchunk[64 x 64] = relu(X @ W1chunk + b1). wave w owns cols w*16..w*16+15.
        f32x4 hacc[4];
        #pragma unroll
        for (int mi = 0; mi < 4; ++mi) hacc[mi] = vzero;
        const int ncol = c * 64 + wave * 16 + l16;       // hidden index (B-frag n = lane&15)
        const unsigned short* w1p = W1T + (size_t)ncol * 128 + q * 8;
        #pragma unroll
        for (int ks = 0; ks < 4; ++ks) {
            bf16x8 bfrag = *(const bf16x8*)(w1p + ks * 32);
            #pragma unroll
            for (int mi = 0; mi < 4; ++mi) {
                bf16x8 afrag = *(const bf16x8*)&Xs[mi * 16 + l16][ks * 32 + q * 8];
                hacc[mi] = __builtin_amdgcn_mfma_f32_16x16x32_bf16(afrag, bfrag, hacc[mi], 0, 0, 0);
            }
        }
        const float bias = b1[ncol];
        __syncthreads();   // previous chunk's phase B done reading Hs
        #pragma unroll
        for (int mi = 0; mi < 4; ++mi) {
            #pragma unroll
            for (int rg = 0; rg < 4; ++rg) {
                float v = hacc[mi][rg] + bias;
                v = fmaxf(v, 0.0f);
                Hs[mi * 16 + q * 4 + rg][wave * 16 + l16] = f2bf(v);
            }
        }
        __syncthreads();
        // phase B: acc += Hchunk @ W2chunk. wave w owns out cols w*64..w*64+63.
        const unsigned short* w2p = W2T + c * 64 + q * 8;
        #pragma unroll
        for (int ks = 0; ks < 2; ++ks) {
            bf16x8 afr[4], bfr[4];
            #pragma unroll
            for (int mi = 0; mi < 4; ++mi)
                afr[mi] = *(const bf16x8*)&Hs[mi * 16 + l16][ks * 32 + q * 8];
            #pragma unroll
            for (int ni = 0; ni < 4; ++ni)
                bfr[ni] = *(const bf16x8*)(w2p + (size_t)(wave * 64 + ni * 16 + l16) * 1024 + ks * 32);
            #pragma unroll
            for (int mi = 0; mi < 4; ++mi)
                #pragma unroll
                for (int ni = 0; ni < 4; ++ni)
                    acc[mi][ni] = __builtin_amdgcn_mfma_f32_16x16x32_bf16(afr[mi], bfr[ni], acc[mi][ni], 0, 0, 0);
        }
    }

    // ---------------- epilogue: + b2, store f32 ----------------
    #pragma unroll
    for (int ni = 0; ni < 4; ++ni) {
        const int n = wave * 64 + ni * 16 + l16;
        const float bb = b2[n];
        #pragma unroll
        for (int mi = 0; mi < 4; ++mi) {
            #pragma unroll
            for (int rg = 0; rg < 4; ++rg) {
                const long row = r0 + mi * 16 + q * 4 + rg;
                out[row * 256 + n] = acc[mi][ni][rg] + bb;
            }
        }
    }
}

extern "C" void kernel_launch(void* const* d_in, const int* in_sizes, int n_in,
                              void* d_out, int out_size, void* d_ws, size_t ws_size,
                              hipStream_t stream) {
    (void)in_sizes; (void)n_in; (void)out_size; (void)ws_size;
    const float* hole  = (const float*)d_in[0];
    const float* board = (const float*)d_in[1];
    const float* W1    = (const float*)d_in[2];
    const float* b1    = (const float*)d_in[3];
    const float* W2    = (const float*)d_in[4];
    const float* b2    = (const float*)d_in[5];
    float* out = (float*)d_out;

    unsigned short* W1T = (unsigned short*)d_ws;            // 1024*128 bf16 = 256 KB
    unsigned short* W2T = W1T + 1024 * 128;                 // 256*1024 bf16 = 512 KB

    conv_w1<<<512, 256, 0, stream>>>(W1, W1T);
    conv_w2<<<1024, 256, 0, stream>>>(W2, W2T);
    mlp_fused<<<131072 / 64, 256, 0, stream>>>(hole, board, b1, b2, W1T, W2T, out);
}